// Round 8
// baseline (588.386 us; speedup 1.0000x reference)
//
#include <hip/hip_runtime.h>
#include <math.h>

#define HID 128
#define NSTEPS 64
#define SLEN 65
#define THREADS 256
#define ROWS 64
#define ASTRIDE 136   // 128 + 8 f16 pad, 16B aligned rows
#define FSTRIDE 40    // 32 + 8 f16 pad
#define DSTR 68       // 64 + 4 f32 pad, 16B-aligned rows for b128 flush reads

typedef _Float16 half8 __attribute__((ext_vector_type(8)));
typedef __fp16 fp16x2 __attribute__((ext_vector_type(2)));
typedef float floatx4 __attribute__((ext_vector_type(4)));

// R20 = R19 + G2 deleted algebraically (4 phases, 4 barriers/step).
//   v  = lrelu(h0@sW1 + u@W25 + cvec),  W25 = rW2@sW1, cvec = rb2@sW1+sb1
//   d  = sigmoid(h0.Wf + u.wfu + v.ws2f + C), wfu = rW2@Wf, C = (rb2+sb2).Wf+bf
// h1 is never materialized. h0/u/v live in bufA/bufB/bufC so the WF phase
// reads all three dot-chains with ZERO cross-barrier register liveness
// (R18's spill mode structurally avoided; wfrag stays 3 matrices = 96 VGPR).
// W25 is computed on-device at init with the kernel's own GEMM: stage rW2
// half into bufA, GEMM vs already-loaded sW1 frags, EPI to bufB, gather
// B-frags (2 passes, ~2us). Slds dropped to fit bufC (75.5KB <= 80KB,
// 2 WGs/CU kept); S read per-step from global (64x4B, L2-resident,
// prefetches under G1 -- pre-R13 pattern).
// R19 lesson kept: WRITE_SIZE == out (8.19MB) is the spill gate; R12/R13
// carried ~20MB hidden scratch until wfrag shrank.
// CLOSED: cols/wave != 32 (R3 spill; R16/R17 traffic law ~128/colsPerWave);
// min-waves>2 (R15 FETCH 3.2GB); XOR swizzle (R14: conflicts structural);
// acc live across barriers (R18); 32x32 MFMA; Slds+scattered-out both
// optional (R13 win was mostly spill, not staging).
__global__ __launch_bounds__(THREADS, 2)
void hedger(const float* __restrict__ S,
            const float* __restrict__ W0,  const float* __restrict__ b0,
            const float* __restrict__ rW1, const float* __restrict__ rb1,
            const float* __restrict__ rW2, const float* __restrict__ rb2,
            const float* __restrict__ sW1, const float* __restrict__ sb1,
            const float* __restrict__ sW2, const float* __restrict__ sb2,
            const float* __restrict__ Wf,  const float* __restrict__ bfp,
            float* __restrict__ out)
{
  __shared__ __align__(16) _Float16 bufA[ROWS * ASTRIDE];   // h0   (17408 B)
  __shared__ __align__(16) _Float16 bufB[ROWS * ASTRIDE];   // u    (17408 B)
  __shared__ __align__(16) _Float16 bufC[ROWS * ASTRIDE];   // v    (17408 B)
  __shared__ __align__(16) _Float16 featb[ROWS * FSTRIDE];  //       5120 B
  __shared__ __align__(16) _Float16 WfS[HID];               //        256 B
  __shared__ __align__(16) _Float16 WfuS[HID];              // rW2@Wf  256 B
  __shared__ __align__(16) _Float16 Ws2S[HID];              // sW2@Wf  256 B
  __shared__             float    CvalS;
  __shared__ __align__(16) float    deltab[ROWS * DSTR];    //      17408 B
  // total ~75.5 KB -> 2 WGs/CU (<= 80 KB each)

  const int tid  = threadIdx.x;
  const int wave = tid >> 6;            // 0..3
  const int lane = tid & 63;
  const int l15  = lane & 15;
  const int quad = lane >> 4;
  const int n_base = wave * 32;
  const int r0 = blockIdx.x * ROWS;
  const int col0 = n_base + 2 * l15;    // lane's adjacent column pair

  // ---- persistent B fragments (96 VGPR): m=0 rW1, m=1 sW1, m=2 W25.
  half8 wfrag[3][4][2];  // [matrix][kIter][nt]
  {
    const float* Wm[2] = {rW1, sW1};
#pragma unroll
    for (int m = 0; m < 2; ++m)
#pragma unroll
      for (int kq = 0; kq < 4; ++kq)
#pragma unroll
        for (int nt = 0; nt < 2; ++nt) {
          const int n  = col0 + nt;
          const int kb = kq * 32 + quad * 8;
          half8 f;
#pragma unroll
          for (int j = 0; j < 8; ++j)
            f[j] = (_Float16)Wm[m][(kb + j) * HID + n];
          wfrag[m][kq][nt] = f;
        }
  }
  // W0 (8x128) zero-padded to K=32: only quad 0 (k<8) is real.
  half8 w0frag[2];
#pragma unroll
  for (int nt = 0; nt < 2; ++nt) {
    const int n = col0 + nt;
    half8 f;
#pragma unroll
    for (int j = 0; j < 8; ++j) {
      const int k = quad * 8 + j;
      f[j] = (k < 8) ? (_Float16)W0[k * HID + n] : (_Float16)0.f;
    }
    w0frag[nt] = f;
  }
  // biases: b0, rb1 direct; cvec = rb2@sW1 + sb1 via the lane's own sW1
  // fragments (quads partition k; shfl_xor 16/32 completes the dot).
  float b0r[2], rb1r[2], cv[2];
#pragma unroll
  for (int nt = 0; nt < 2; ++nt) {
    const int n = col0 + nt;
    b0r[nt] = b0[n]; rb1r[nt] = rb1[n];
    float p = 0.f;
#pragma unroll
    for (int kq = 0; kq < 4; ++kq) {
      const int kb = kq * 32 + quad * 8;
#pragma unroll
      for (int j = 0; j < 8; ++j)
        p += rb2[kb + j] * (float)wfrag[1][kq][nt][j];
    }
    p += __shfl_xor(p, 16);
    p += __shfl_xor(p, 32);
    cv[nt] = p + sb1[n];
  }

  // LDS init: featb zero-fill (pad cols 8..31 stay zero), Wf / wfu / ws2f
  // vectors, C scalar.
  for (int i = tid; i < ROWS * FSTRIDE; i += THREADS) featb[i] = (_Float16)0.f;
  if (tid < HID) {
    WfS[tid] = (_Float16)Wf[tid];
    float su = 0.f, ss = 0.f;
    for (int n = 0; n < HID; ++n) {
      su += rW2[tid * HID + n] * Wf[n];
      ss += sW2[tid * HID + n] * Wf[n];
    }
    WfuS[tid] = (_Float16)su;
    Ws2S[tid] = (_Float16)ss;
  }
  if (wave == 0) {   // C = (rb2 + sb2).Wf + bf
    float p = (rb2[lane] + sb2[lane]) * Wf[lane]
            + (rb2[lane + 64] + sb2[lane + 64]) * Wf[lane + 64];
    p += __shfl_xor(p, 1);  p += __shfl_xor(p, 2);  p += __shfl_xor(p, 4);
    p += __shfl_xor(p, 8);  p += __shfl_xor(p, 16); p += __shfl_xor(p, 32);
    if (lane == 0) CvalS = p + bfp[0];
  }

  floatx4 acc[4][2];

#define INIT_BIAS(BR) do { \
  _Pragma("unroll") for (int mt = 0; mt < 4; ++mt) \
  _Pragma("unroll") for (int nt = 0; nt < 2; ++nt) { \
    floatx4 z = {BR[nt], BR[nt], BR[nt], BR[nt]}; acc[mt][nt] = z; } } while (0)

#define GEMM128(SRC, MI) do { \
  _Pragma("unroll") for (int kq = 0; kq < 4; ++kq) { \
    half8 afr[4]; \
    _Pragma("unroll") for (int mt = 0; mt < 4; ++mt) \
      afr[mt] = *(const half8*)&SRC[(mt * 16 + l15) * ASTRIDE + kq * 32 + quad * 8]; \
    _Pragma("unroll") for (int mt = 0; mt < 4; ++mt) \
    _Pragma("unroll") for (int nt = 0; nt < 2; ++nt) \
      acc[mt][nt] = __builtin_amdgcn_mfma_f32_16x16x32_f16( \
          afr[mt], wfrag[MI][kq][nt], acc[mt][nt], 0, 0, 0); \
  } } while (0)

#define EPI_LRELU(DST) do { \
  _Pragma("unroll") for (int mt = 0; mt < 4; ++mt) \
  _Pragma("unroll") for (int r = 0; r < 4; ++r) { \
    const int row = mt * 16 + quad * 4 + r; \
    const float v0 = acc[mt][0][r]; \
    const float v1 = acc[mt][1][r]; \
    fp16x2 h2 = {(__fp16)fmaxf(v0, 0.2f * v0), (__fp16)fmaxf(v1, 0.2f * v1)}; \
    *(fp16x2*)&DST[row * ASTRIDE + col0] = h2; \
  } } while (0)

#define EPI_STORE(DST) do { \
  _Pragma("unroll") for (int mt = 0; mt < 4; ++mt) \
  _Pragma("unroll") for (int r = 0; r < 4; ++r) { \
    const int row = mt * 16 + quad * 4 + r; \
    fp16x2 h2 = {(__fp16)acc[mt][0][r], (__fp16)acc[mt][1][r]}; \
    *(fp16x2*)&DST[row * ASTRIDE + col0] = h2; \
  } } while (0)

  // ---- init-time W25 = rW2 @ sW1 via the GEMM machinery (2 half passes).
  // Stage rW2 rows [h*64, h*64+64) f16 into bufA, GEMM vs wfrag[1]=sW1,
  // EPI f16 into bufB, gather this half's B-fragments.
#pragma unroll 1
  for (int h = 0; h < 2; ++h) {
    __syncthreads();                       // bufA/bufB free (also covers featb fill)
    for (int i = tid; i < ROWS * HID; i += THREADS) {
      const int row = i >> 7, c = i & 127;
      bufA[row * ASTRIDE + c] = (_Float16)rW2[(h * 64 + row) * HID + c];
    }
    __syncthreads();
    {
      float zr[2] = {0.f, 0.f};
      INIT_BIAS(zr);
      GEMM128(bufA, 1);
      EPI_STORE(bufB);
    }
    __syncthreads();
#pragma unroll
    for (int kqh = 0; kqh < 2; ++kqh) {
      const int kq = h * 2 + kqh;
      half8 f0, f1;
#pragma unroll
      for (int j = 0; j < 8; ++j) {
        const int kl = kq * 32 + quad * 8 + j - h * 64;   // 0..63
        const fp16x2 p = *(const fp16x2*)&bufB[kl * ASTRIDE + col0];
        f0[j] = (_Float16)p[0];
        f1[j] = (_Float16)p[1];
      }
      wfrag[2][kq][0] = f0;
      wfrag[2][kq][1] = f1;
    }
  }
  __syncthreads();   // gathers done; bufA/bufB return to loop use

  // step-0 features (threads 0..63 each own one row; S read from global)
  float lm_prev = 0.f, cum_x = 0.f, qv = 0.f;
  const float* Srow = S + (size_t)(r0 + (tid & (ROWS - 1))) * SLEN;
  if (tid < ROWS) {
    const float lm = logf(Srow[0] * 0.01f);
    lm_prev = lm; cum_x = lm; qv = 0.f;
    _Float16* fr = &featb[tid * FSTRIDE];
    fr[0] = (_Float16)lm;
    fr[1] = (_Float16)1.0f;
    fr[2] = (_Float16)0.235f;
    fr[3] = (_Float16)0.f;                 // delta_0 = 0
    fr[4] = (_Float16)lm;                  // run_mean at k=0
    fr[5] = (_Float16)0.f;
    fr[6] = (_Float16)(1.9f * sqrtf(1e-12f));
    fr[7] = (_Float16)0.f;
  }
  __syncthreads();
  const float Cval = CvalS;

#pragma unroll 1
  for (int k = 0; k < NSTEPS; ++k) {
    // G0: h0 = lrelu(featPad @ W0pad + b0)
    INIT_BIAS(b0r);
    {
      half8 afr[4];
#pragma unroll
      for (int mt = 0; mt < 4; ++mt)
        afr[mt] = *(const half8*)&featb[(mt * 16 + l15) * FSTRIDE + quad * 8];
#pragma unroll
      for (int mt = 0; mt < 4; ++mt)
#pragma unroll
        for (int nt = 0; nt < 2; ++nt)
          acc[mt][nt] = __builtin_amdgcn_mfma_f32_16x16x32_f16(
              afr[mt], w0frag[nt], acc[mt][nt], 0, 0, 0);
    }
    EPI_LRELU(bufA);
    __syncthreads();                                   // bar A: h0 in bufA

    // delta-independent features of step k+1 — overlaps G1.
    // (Srow[k+1] valid at k=63: SLEN=65; write is dead then, harmless.)
    if (tid < ROWS) {
      const int kk = k + 1;
      const float lm = logf(Srow[kk] * 0.01f);
      const float rr = lm - lm_prev; qv += rr * rr;
      lm_prev = lm; cum_x += lm;
      const float tT = (float)kk * (1.f / 64.f);
      _Float16* fr = &featb[tid * FSTRIDE];
      fr[0] = (_Float16)lm;
      fr[1] = (_Float16)(1.f - tT);
      fr[4] = (_Float16)(cum_x / (float)(kk + 1));
      fr[5] = (_Float16)qv;
      fr[6] = (_Float16)(1.9f * sqrtf(qv + 1e-12f));
      fr[7] = (_Float16)tT;
    }

    // G1: u = lrelu(h0 @ rW1 + rb1)
    INIT_BIAS(rb1r);  GEMM128(bufA, 0);  EPI_LRELU(bufB);
    __syncthreads();                                   // bar B: u in bufB

    // G23: v = lrelu(h0 @ sW1 + u @ W25 + cvec)   (G2 deleted)
    INIT_BIAS(cv);
    GEMM128(bufA, 1);
    GEMM128(bufB, 2);
    EPI_LRELU(bufC);
    __syncthreads();                                   // bar C: v in bufC

    // WF: delta = sigmoid(h0.Wf + u.wfu + v.ws2f + C), three independent
    // broadcast-B MFMA chains; no cross-barrier register liveness.
    {
      floatx4 d1 = {0.f, 0.f, 0.f, 0.f};
      floatx4 d2 = {0.f, 0.f, 0.f, 0.f};
      floatx4 d3 = {0.f, 0.f, 0.f, 0.f};
      const int arow = (wave * 16 + l15) * ASTRIDE;
#pragma unroll
      for (int kq = 0; kq < 4; ++kq) {
        const int off = kq * 32 + quad * 8;
        const half8 a1 = *(const half8*)&bufA[arow + off];
        const half8 w1 = *(const half8*)&WfS[off];
        d1 = __builtin_amdgcn_mfma_f32_16x16x32_f16(a1, w1, d1, 0, 0, 0);
        const half8 a2 = *(const half8*)&bufB[arow + off];
        const half8 w2 = *(const half8*)&WfuS[off];
        d2 = __builtin_amdgcn_mfma_f32_16x16x32_f16(a2, w2, d2, 0, 0, 0);
        const half8 a3 = *(const half8*)&bufC[arow + off];
        const half8 w3 = *(const half8*)&Ws2S[off];
        d3 = __builtin_amdgcn_mfma_f32_16x16x32_f16(a3, w3, d3, 0, 0, 0);
      }
      if (l15 < 4) {
        // static-index select (rule: no runtime vector index)
        const float s1 = (l15 & 2) ? ((l15 & 1) ? d1[3] : d1[2])
                                   : ((l15 & 1) ? d1[1] : d1[0]);
        const float s2 = (l15 & 2) ? ((l15 & 1) ? d2[3] : d2[2])
                                   : ((l15 & 1) ? d2[1] : d2[0]);
        const float s3 = (l15 & 2) ? ((l15 & 1) ? d3[3] : d3[2])
                                   : ((l15 & 1) ? d3[1] : d3[0]);
        const int row = wave * 16 + quad * 4 + l15;
        const float d = 1.f / (1.f + expf(-(s1 + s2 + s3 + Cval)));
        featb[row * FSTRIDE + 3] = (_Float16)d;        // fr[3] for step k+1
        deltab[row * DSTR + k] = d;                    // staged output
      }
    }
    __syncthreads();                                   // bar D: featb complete
  }

  // coalesced output flush: 64 rows x 64 steps, dwordx4 stores.
  {
    const int row = tid >> 2;                // 0..63
    const int c0  = (tid & 3) * 16;          // 0,16,32,48
    const float* dr = &deltab[row * DSTR + c0];
    float* orow = &out[(size_t)(r0 + row) * NSTEPS + c0];
#pragma unroll
    for (int u = 0; u < 4; ++u) {
      const floatx4 v = *(const floatx4*)&dr[u * 4];
      *(floatx4*)&orow[u * 4] = v;
    }
  }
#undef INIT_BIAS
#undef GEMM128
#undef EPI_LRELU
#undef EPI_STORE
}

extern "C" void kernel_launch(void* const* d_in, const int* in_sizes, int n_in,
                              void* d_out, int out_size, void* d_ws, size_t ws_size,
                              hipStream_t stream) {
  const float* S   = (const float*)d_in[0];
  const float* W0  = (const float*)d_in[1];
  const float* b0  = (const float*)d_in[2];
  const float* rW1 = (const float*)d_in[3];
  const float* rb1 = (const float*)d_in[4];
  const float* rW2 = (const float*)d_in[5];
  const float* rb2 = (const float*)d_in[6];
  const float* sW1 = (const float*)d_in[7];
  const float* sb1 = (const float*)d_in[8];
  const float* sW2 = (const float*)d_in[9];
  const float* sb2 = (const float*)d_in[10];
  const float* Wf  = (const float*)d_in[11];
  const float* bf  = (const float*)d_in[12];
  float* out = (float*)d_out;

  const int B = out_size / NSTEPS;        // 32768
  const int nblocks = B / ROWS;           // 512 WGs -> 2 per CU
  hedger<<<nblocks, THREADS, 0, stream>>>(
      S, W0, b0, rW1, rb1, rW2, rb2, sW1, sb1, sW2, sb2, Wf, bf, out);
}

// Round 9
// 339.972 us; speedup vs baseline: 1.7307x; 1.7307x over previous
//
#include <hip/hip_runtime.h>
#include <math.h>

#define HID 128
#define NSTEPS 64
#define SLEN 65
#define THREADS 256
#define ROWS 64
#define ASTRIDE 136   // 128 + 8 f16 pad, 16B aligned rows
#define FSTRIDE 40    // 32 + 8 f16 pad
#define DSTR 68       // 64 + 4 f32 pad, 16B-aligned rows for b128 flush reads

typedef _Float16 half8 __attribute__((ext_vector_type(8)));
typedef __fp16 fp16x2 __attribute__((ext_vector_type(2)));
typedef float floatx4 __attribute__((ext_vector_type(4)));

// R21 = R20 with the rule-#20 violation fixed. R20's 549us/1.7GB-FETCH was
// NOT the algebra: the W25 init loop was `#pragma unroll 1 for(h)`, making
// wfrag[2][h*2+kqh][nt] a RUNTIME index -> the whole wfrag array (96 VGPR)
// was allocated in scratch -> every hot-loop GEMM re-read B-frags from
// memory (~3GB). Fix: fully unroll h so all wfrag indices are compile-time.
// Structure (from R20): 4 phases, 4 barriers/step. G2 deleted:
//   v = lrelu(h0@sW1 + u@W25 + cvec),  W25 = rW2@sW1 (on-device init GEMM),
//   d = sigmoid(h0.Wf + u.wfu + v.ws2f + C)  -- three broadcast-B chains,
// h0/u/v in bufA/B/C, zero cross-barrier register liveness.
// Spill gate: WRITE_SIZE must stay ~= out (8.2MB) and FETCH ~6-8MB.
// CLOSED: cols/wave != 32 (R3; R16/R17 traffic law 128/colsPerWave);
// min-waves>2 (R15); XOR swizzle (R14 structural conflicts); acc live
// across barriers (R18 spill); runtime-indexed frag arrays (R20, rule #20).
__global__ __launch_bounds__(THREADS, 2)
void hedger(const float* __restrict__ S,
            const float* __restrict__ W0,  const float* __restrict__ b0,
            const float* __restrict__ rW1, const float* __restrict__ rb1,
            const float* __restrict__ rW2, const float* __restrict__ rb2,
            const float* __restrict__ sW1, const float* __restrict__ sb1,
            const float* __restrict__ sW2, const float* __restrict__ sb2,
            const float* __restrict__ Wf,  const float* __restrict__ bfp,
            float* __restrict__ out)
{
  __shared__ __align__(16) _Float16 bufA[ROWS * ASTRIDE];   // h0   (17408 B)
  __shared__ __align__(16) _Float16 bufB[ROWS * ASTRIDE];   // u    (17408 B)
  __shared__ __align__(16) _Float16 bufC[ROWS * ASTRIDE];   // v    (17408 B)
  __shared__ __align__(16) _Float16 featb[ROWS * FSTRIDE];  //       5120 B
  __shared__ __align__(16) _Float16 WfS[HID];               //        256 B
  __shared__ __align__(16) _Float16 WfuS[HID];              // rW2@Wf  256 B
  __shared__ __align__(16) _Float16 Ws2S[HID];              // sW2@Wf  256 B
  __shared__             float    CvalS;
  __shared__ __align__(16) float    deltab[ROWS * DSTR];    //      17408 B
  // total ~75.5 KB -> 2 WGs/CU

  const int tid  = threadIdx.x;
  const int wave = tid >> 6;            // 0..3
  const int lane = tid & 63;
  const int l15  = lane & 15;
  const int quad = lane >> 4;
  const int n_base = wave * 32;
  const int r0 = blockIdx.x * ROWS;
  const int col0 = n_base + 2 * l15;    // lane's adjacent column pair

  // ---- persistent B fragments (96 VGPR): m=0 rW1, m=1 sW1, m=2 W25.
  half8 wfrag[3][4][2];  // [matrix][kIter][nt]
  {
    const float* Wm[2] = {rW1, sW1};
#pragma unroll
    for (int m = 0; m < 2; ++m)
#pragma unroll
      for (int kq = 0; kq < 4; ++kq)
#pragma unroll
        for (int nt = 0; nt < 2; ++nt) {
          const int n  = col0 + nt;
          const int kb = kq * 32 + quad * 8;
          half8 f;
#pragma unroll
          for (int j = 0; j < 8; ++j)
            f[j] = (_Float16)Wm[m][(kb + j) * HID + n];
          wfrag[m][kq][nt] = f;
        }
  }
  // W0 (8x128) zero-padded to K=32: only quad 0 (k<8) is real.
  half8 w0frag[2];
#pragma unroll
  for (int nt = 0; nt < 2; ++nt) {
    const int n = col0 + nt;
    half8 f;
#pragma unroll
    for (int j = 0; j < 8; ++j) {
      const int k = quad * 8 + j;
      f[j] = (k < 8) ? (_Float16)W0[k * HID + n] : (_Float16)0.f;
    }
    w0frag[nt] = f;
  }
  // biases: b0, rb1 direct; cvec = rb2@sW1 + sb1 via the lane's own sW1
  // fragments (quads partition k; shfl_xor 16/32 completes the dot).
  float b0r[2], rb1r[2], cv[2];
#pragma unroll
  for (int nt = 0; nt < 2; ++nt) {
    const int n = col0 + nt;
    b0r[nt] = b0[n]; rb1r[nt] = rb1[n];
    float p = 0.f;
#pragma unroll
    for (int kq = 0; kq < 4; ++kq) {
      const int kb = kq * 32 + quad * 8;
#pragma unroll
      for (int j = 0; j < 8; ++j)
        p += rb2[kb + j] * (float)wfrag[1][kq][nt][j];
    }
    p += __shfl_xor(p, 16);
    p += __shfl_xor(p, 32);
    cv[nt] = p + sb1[n];
  }

  // LDS init: featb zero-fill (pad cols 8..31 stay zero), Wf / wfu / ws2f
  // vectors, C scalar.
  for (int i = tid; i < ROWS * FSTRIDE; i += THREADS) featb[i] = (_Float16)0.f;
  if (tid < HID) {
    WfS[tid] = (_Float16)Wf[tid];
    float su = 0.f, ss = 0.f;
    for (int n = 0; n < HID; ++n) {
      su += rW2[tid * HID + n] * Wf[n];
      ss += sW2[tid * HID + n] * Wf[n];
    }
    WfuS[tid] = (_Float16)su;
    Ws2S[tid] = (_Float16)ss;
  }
  if (wave == 0) {   // C = (rb2 + sb2).Wf + bf
    float p = (rb2[lane] + sb2[lane]) * Wf[lane]
            + (rb2[lane + 64] + sb2[lane + 64]) * Wf[lane + 64];
    p += __shfl_xor(p, 1);  p += __shfl_xor(p, 2);  p += __shfl_xor(p, 4);
    p += __shfl_xor(p, 8);  p += __shfl_xor(p, 16); p += __shfl_xor(p, 32);
    if (lane == 0) CvalS = p + bfp[0];
  }

  floatx4 acc[4][2];

#define INIT_BIAS(BR) do { \
  _Pragma("unroll") for (int mt = 0; mt < 4; ++mt) \
  _Pragma("unroll") for (int nt = 0; nt < 2; ++nt) { \
    floatx4 z = {BR[nt], BR[nt], BR[nt], BR[nt]}; acc[mt][nt] = z; } } while (0)

#define GEMM128(SRC, MI) do { \
  _Pragma("unroll") for (int kq = 0; kq < 4; ++kq) { \
    half8 afr[4]; \
    _Pragma("unroll") for (int mt = 0; mt < 4; ++mt) \
      afr[mt] = *(const half8*)&SRC[(mt * 16 + l15) * ASTRIDE + kq * 32 + quad * 8]; \
    _Pragma("unroll") for (int mt = 0; mt < 4; ++mt) \
    _Pragma("unroll") for (int nt = 0; nt < 2; ++nt) \
      acc[mt][nt] = __builtin_amdgcn_mfma_f32_16x16x32_f16( \
          afr[mt], wfrag[MI][kq][nt], acc[mt][nt], 0, 0, 0); \
  } } while (0)

#define EPI_LRELU(DST) do { \
  _Pragma("unroll") for (int mt = 0; mt < 4; ++mt) \
  _Pragma("unroll") for (int r = 0; r < 4; ++r) { \
    const int row = mt * 16 + quad * 4 + r; \
    const float v0 = acc[mt][0][r]; \
    const float v1 = acc[mt][1][r]; \
    fp16x2 h2 = {(__fp16)fmaxf(v0, 0.2f * v0), (__fp16)fmaxf(v1, 0.2f * v1)}; \
    *(fp16x2*)&DST[row * ASTRIDE + col0] = h2; \
  } } while (0)

#define EPI_STORE(DST) do { \
  _Pragma("unroll") for (int mt = 0; mt < 4; ++mt) \
  _Pragma("unroll") for (int r = 0; r < 4; ++r) { \
    const int row = mt * 16 + quad * 4 + r; \
    fp16x2 h2 = {(__fp16)acc[mt][0][r], (__fp16)acc[mt][1][r]}; \
    *(fp16x2*)&DST[row * ASTRIDE + col0] = h2; \
  } } while (0)

  // ---- init-time W25 = rW2 @ sW1 via the GEMM machinery (2 half passes).
  // FULLY UNROLLED over h (rule #20): every wfrag[2][kq][nt] index below is
  // a compile-time constant, keeping wfrag in VGPRs.
#pragma unroll
  for (int h = 0; h < 2; ++h) {
    __syncthreads();                       // bufA/bufB free (also covers featb fill)
    for (int i = tid; i < ROWS * HID; i += THREADS) {
      const int row = i >> 7, c = i & 127;
      bufA[row * ASTRIDE + c] = (_Float16)rW2[(h * 64 + row) * HID + c];
    }
    __syncthreads();
    {
      float zr[2] = {0.f, 0.f};
      INIT_BIAS(zr);
      GEMM128(bufA, 1);
      EPI_STORE(bufB);
    }
    __syncthreads();
#pragma unroll
    for (int kqh = 0; kqh < 2; ++kqh) {
      const int kq = h * 2 + kqh;          // compile-time (h, kqh unrolled)
      half8 f0, f1;
#pragma unroll
      for (int j = 0; j < 8; ++j) {
        const int kl = kq * 32 + quad * 8 + j - h * 64;   // 0..63
        const fp16x2 p = *(const fp16x2*)&bufB[kl * ASTRIDE + col0];
        f0[j] = (_Float16)p[0];
        f1[j] = (_Float16)p[1];
      }
      wfrag[2][kq][0] = f0;
      wfrag[2][kq][1] = f1;
    }
  }
  __syncthreads();   // gathers done; bufA/bufB return to loop use

  // step-0 features (threads 0..63 each own one row; S read from global)
  float lm_prev = 0.f, cum_x = 0.f, qv = 0.f;
  const float* Srow = S + (size_t)(r0 + (tid & (ROWS - 1))) * SLEN;
  if (tid < ROWS) {
    const float lm = logf(Srow[0] * 0.01f);
    lm_prev = lm; cum_x = lm; qv = 0.f;
    _Float16* fr = &featb[tid * FSTRIDE];
    fr[0] = (_Float16)lm;
    fr[1] = (_Float16)1.0f;
    fr[2] = (_Float16)0.235f;
    fr[3] = (_Float16)0.f;                 // delta_0 = 0
    fr[4] = (_Float16)lm;                  // run_mean at k=0
    fr[5] = (_Float16)0.f;
    fr[6] = (_Float16)(1.9f * sqrtf(1e-12f));
    fr[7] = (_Float16)0.f;
  }
  __syncthreads();
  const float Cval = CvalS;

#pragma unroll 1
  for (int k = 0; k < NSTEPS; ++k) {
    // G0: h0 = lrelu(featPad @ W0pad + b0)
    INIT_BIAS(b0r);
    {
      half8 afr[4];
#pragma unroll
      for (int mt = 0; mt < 4; ++mt)
        afr[mt] = *(const half8*)&featb[(mt * 16 + l15) * FSTRIDE + quad * 8];
#pragma unroll
      for (int mt = 0; mt < 4; ++mt)
#pragma unroll
        for (int nt = 0; nt < 2; ++nt)
          acc[mt][nt] = __builtin_amdgcn_mfma_f32_16x16x32_f16(
              afr[mt], w0frag[nt], acc[mt][nt], 0, 0, 0);
    }
    EPI_LRELU(bufA);
    __syncthreads();                                   // bar A: h0 in bufA

    // delta-independent features of step k+1 — overlaps G1.
    // (Srow[k+1] valid at k=63: SLEN=65; write is dead then, harmless.)
    if (tid < ROWS) {
      const int kk = k + 1;
      const float lm = logf(Srow[kk] * 0.01f);
      const float rr = lm - lm_prev; qv += rr * rr;
      lm_prev = lm; cum_x += lm;
      const float tT = (float)kk * (1.f / 64.f);
      _Float16* fr = &featb[tid * FSTRIDE];
      fr[0] = (_Float16)lm;
      fr[1] = (_Float16)(1.f - tT);
      fr[4] = (_Float16)(cum_x / (float)(kk + 1));
      fr[5] = (_Float16)qv;
      fr[6] = (_Float16)(1.9f * sqrtf(qv + 1e-12f));
      fr[7] = (_Float16)tT;
    }

    // G1: u = lrelu(h0 @ rW1 + rb1)
    INIT_BIAS(rb1r);  GEMM128(bufA, 0);  EPI_LRELU(bufB);
    __syncthreads();                                   // bar B: u in bufB

    // G23: v = lrelu(h0 @ sW1 + u @ W25 + cvec)   (G2 deleted)
    INIT_BIAS(cv);
    GEMM128(bufA, 1);
    GEMM128(bufB, 2);
    EPI_LRELU(bufC);
    __syncthreads();                                   // bar C: v in bufC

    // WF: delta = sigmoid(h0.Wf + u.wfu + v.ws2f + C), three independent
    // broadcast-B MFMA chains; no cross-barrier register liveness.
    {
      floatx4 d1 = {0.f, 0.f, 0.f, 0.f};
      floatx4 d2 = {0.f, 0.f, 0.f, 0.f};
      floatx4 d3 = {0.f, 0.f, 0.f, 0.f};
      const int arow = (wave * 16 + l15) * ASTRIDE;
#pragma unroll
      for (int kq = 0; kq < 4; ++kq) {
        const int off = kq * 32 + quad * 8;
        const half8 a1 = *(const half8*)&bufA[arow + off];
        const half8 w1 = *(const half8*)&WfS[off];
        d1 = __builtin_amdgcn_mfma_f32_16x16x32_f16(a1, w1, d1, 0, 0, 0);
        const half8 a2 = *(const half8*)&bufB[arow + off];
        const half8 w2 = *(const half8*)&WfuS[off];
        d2 = __builtin_amdgcn_mfma_f32_16x16x32_f16(a2, w2, d2, 0, 0, 0);
        const half8 a3 = *(const half8*)&bufC[arow + off];
        const half8 w3 = *(const half8*)&Ws2S[off];
        d3 = __builtin_amdgcn_mfma_f32_16x16x32_f16(a3, w3, d3, 0, 0, 0);
      }
      if (l15 < 4) {
        // static-index select (rule: no runtime vector index)
        const float s1 = (l15 & 2) ? ((l15 & 1) ? d1[3] : d1[2])
                                   : ((l15 & 1) ? d1[1] : d1[0]);
        const float s2 = (l15 & 2) ? ((l15 & 1) ? d2[3] : d2[2])
                                   : ((l15 & 1) ? d2[1] : d2[0]);
        const float s3 = (l15 & 2) ? ((l15 & 1) ? d3[3] : d3[2])
                                   : ((l15 & 1) ? d3[1] : d3[0]);
        const int row = wave * 16 + quad * 4 + l15;
        const float d = 1.f / (1.f + expf(-(s1 + s2 + s3 + Cval)));
        featb[row * FSTRIDE + 3] = (_Float16)d;        // fr[3] for step k+1
        deltab[row * DSTR + k] = d;                    // staged output
      }
    }
    __syncthreads();                                   // bar D: featb complete
  }

  // coalesced output flush: 64 rows x 64 steps, dwordx4 stores.
  {
    const int row = tid >> 2;                // 0..63
    const int c0  = (tid & 3) * 16;          // 0,16,32,48
    const float* dr = &deltab[row * DSTR + c0];
    float* orow = &out[(size_t)(r0 + row) * NSTEPS + c0];
#pragma unroll
    for (int u = 0; u < 4; ++u) {
      const floatx4 v = *(const floatx4*)&dr[u * 4];
      *(floatx4*)&orow[u * 4] = v;
    }
  }
#undef INIT_BIAS
#undef GEMM128
#undef EPI_LRELU
#undef EPI_STORE
}

extern "C" void kernel_launch(void* const* d_in, const int* in_sizes, int n_in,
                              void* d_out, int out_size, void* d_ws, size_t ws_size,
                              hipStream_t stream) {
  const float* S   = (const float*)d_in[0];
  const float* W0  = (const float*)d_in[1];
  const float* b0  = (const float*)d_in[2];
  const float* rW1 = (const float*)d_in[3];
  const float* rb1 = (const float*)d_in[4];
  const float* rW2 = (const float*)d_in[5];
  const float* rb2 = (const float*)d_in[6];
  const float* sW1 = (const float*)d_in[7];
  const float* sb1 = (const float*)d_in[8];
  const float* sW2 = (const float*)d_in[9];
  const float* sb2 = (const float*)d_in[10];
  const float* Wf  = (const float*)d_in[11];
  const float* bf  = (const float*)d_in[12];
  float* out = (float*)d_out;

  const int B = out_size / NSTEPS;        // 32768
  const int nblocks = B / ROWS;           // 512 WGs -> 2 per CU
  hedger<<<nblocks, THREADS, 0, stream>>>(
      S, W0, b0, rW1, rb1, rW2, rb2, sW1, sb1, sW2, sb2, Wf, bf, out);
}